// Round 2
// baseline (11188.505 us; speedup 1.0000x reference)
//
#include <hip/hip_runtime.h>
#include <cstddef>

#define BB 8
#define LL 1024
#define DD 512
#define NH 8
#define HD 64
#define MM (BB * LL)   // 8192 rows

// C[M x N] = A[M x K] @ W[N x K]^T + bias, optional ReLU. fp32.
// grid: (N/64, M/64), block: 256
template <bool RELU>
__global__ __launch_bounds__(256)
void gemm_bias(const float* __restrict__ A,
               const float* __restrict__ W,
               const float* __restrict__ bias,
               float* __restrict__ C, int ldc, int K)
{
    __shared__ float As[16][64];
    __shared__ float Ws[16][64];
    const int tid = threadIdx.x;
    const int m0 = blockIdx.y * 64;
    const int n0 = blockIdx.x * 64;
    const int lr = tid >> 2;          // 0..63 tile row
    const int lk = (tid & 3) << 2;    // 0,4,8,12
    const int tx = tid & 15;
    const int ty = tid >> 4;
    float acc[4][4] = {};
    const float* ap = A + (size_t)(m0 + lr) * K + lk;
    const float* wp = W + (size_t)(n0 + lr) * K + lk;
    for (int kt = 0; kt < K; kt += 16) {
        float4 av = *reinterpret_cast<const float4*>(ap + kt);
        float4 wv = *reinterpret_cast<const float4*>(wp + kt);
        __syncthreads();
        As[lk + 0][lr] = av.x; As[lk + 1][lr] = av.y;
        As[lk + 2][lr] = av.z; As[lk + 3][lr] = av.w;
        Ws[lk + 0][lr] = wv.x; Ws[lk + 1][lr] = wv.y;
        Ws[lk + 2][lr] = wv.z; Ws[lk + 3][lr] = wv.w;
        __syncthreads();
#pragma unroll
        for (int k = 0; k < 16; ++k) {
            float a[4], b[4];
#pragma unroll
            for (int i = 0; i < 4; ++i) a[i] = As[k][ty * 4 + i];
#pragma unroll
            for (int j = 0; j < 4; ++j) b[j] = Ws[k][tx * 4 + j];
#pragma unroll
            for (int i = 0; i < 4; ++i)
#pragma unroll
                for (int j = 0; j < 4; ++j)
                    acc[i][j] = fmaf(a[i], b[j], acc[i][j]);
        }
    }
#pragma unroll
    for (int j = 0; j < 4; ++j) {
        const int n = n0 + tx * 4 + j;
        const float bv = bias[n];
#pragma unroll
        for (int i = 0; i < 4; ++i) {
            const int m = m0 + ty * 4 + i;
            float v = acc[i][j] + bv;
            if (RELU) v = fmaxf(v, 0.f);
            C[(size_t)m * ldc + n] = v;
        }
    }
}

// One block (256 thr) per (b, h, l) query row. qkv: [M x 1536] (q|k|v sections).
// Writes normalized attention weights to wout[(b*NH+h)*L*L + l*L + s] and
// context to ctx[(b*L+l)*512 + h*64 + d].
__global__ __launch_bounds__(256)
void attn_kernel(const float* __restrict__ qkv,
                 float* __restrict__ wout,
                 float* __restrict__ ctx)
{
    __shared__ float sc[LL];
    __shared__ float qs[HD];
    __shared__ float red[256];
    __shared__ float pv[4][HD];

    const int tid = threadIdx.x;
    const int idx = blockIdx.x;
    const int l = idx % LL;
    const int h = (idx / LL) % NH;
    const int b = idx / (LL * NH);

    const float* qrow = qkv + ((size_t)(b * LL + l)) * 1536 + h * HD;
    if (tid < HD) qs[tid] = qrow[tid];
    __syncthreads();

    const float* kbase = qkv + ((size_t)(b * LL)) * 1536 + 512 + h * HD;
    float lmax = -1e30f;
    for (int s = tid; s < LL; s += 256) {
        const float* krow = kbase + (size_t)s * 1536;
        float dot = 0.f;
#pragma unroll
        for (int d = 0; d < HD; d += 4) {
            float4 kv = *reinterpret_cast<const float4*>(krow + d);
            dot = fmaf(qs[d + 0], kv.x, dot);
            dot = fmaf(qs[d + 1], kv.y, dot);
            dot = fmaf(qs[d + 2], kv.z, dot);
            dot = fmaf(qs[d + 3], kv.w, dot);
        }
        dot *= 0.125f;   // 1/sqrt(64)
        sc[s] = dot;
        lmax = fmaxf(lmax, dot);
    }
    red[tid] = lmax;
    __syncthreads();
    for (int off = 128; off > 0; off >>= 1) {
        if (tid < off) red[tid] = fmaxf(red[tid], red[tid + off]);
        __syncthreads();
    }
    const float m = red[0];
    __syncthreads();

    float lsum = 0.f;
    for (int s = tid; s < LL; s += 256) {
        float p = __expf(sc[s] - m);
        sc[s] = p;
        lsum += p;
    }
    red[tid] = lsum;
    __syncthreads();
    for (int off = 128; off > 0; off >>= 1) {
        if (tid < off) red[tid] += red[tid + off];
        __syncthreads();
    }
    const float inv = 1.f / red[0];
    __syncthreads();

    float* wrow = wout + ((size_t)((b * NH + h) * LL + l)) * LL;
    for (int s = tid; s < LL; s += 256)
        wrow[s] = sc[s] * inv;

    // PV: thread (d = tid&63, g = tid>>6) accumulates over s = g, g+4, ...
    const int d = tid & 63;
    const int g = tid >> 6;
    const float* vbase = qkv + ((size_t)(b * LL)) * 1536 + 1024 + h * HD;
    float acc = 0.f;
    for (int s = g; s < LL; s += 4)
        acc = fmaf(sc[s], vbase[(size_t)s * 1536 + d], acc);
    pv[g][d] = acc;
    __syncthreads();
    if (tid < HD) {
        float o = (pv[0][tid] + pv[1][tid] + pv[2][tid] + pv[3][tid]) * inv;
        ctx[((size_t)(b * LL + l)) * DD + h * HD + tid] = o;
    }
}

// y = LN(x + r) * g + b, one block per row of 512. block: 256, 2 elems/thread.
// Safe for out == x (all reads precede first barrier; writes after last).
__global__ __launch_bounds__(256)
void add_ln(const float* __restrict__ x,
            const float* __restrict__ r,
            const float* __restrict__ g,
            const float* __restrict__ b,
            float* __restrict__ out)
{
    __shared__ float red[256];
    const int row = blockIdx.x;
    const int tid = threadIdx.x;
    const size_t base = (size_t)row * DD;
    float v0 = x[base + tid] + r[base + tid];
    float v1 = x[base + tid + 256] + r[base + tid + 256];
    red[tid] = v0 + v1;
    __syncthreads();
    for (int off = 128; off > 0; off >>= 1) {
        if (tid < off) red[tid] += red[tid + off];
        __syncthreads();
    }
    const float mu = red[0] * (1.f / 512.f);
    __syncthreads();
    const float d0 = v0 - mu, d1 = v1 - mu;
    red[tid] = d0 * d0 + d1 * d1;
    __syncthreads();
    for (int off = 128; off > 0; off >>= 1) {
        if (tid < off) red[tid] += red[tid + off];
        __syncthreads();
    }
    const float inv = 1.f / sqrtf(red[0] * (1.f / 512.f) + 1e-5f);
    out[base + tid]       = d0 * inv * g[tid]       + b[tid];
    out[base + tid + 256] = d1 * inv * g[tid + 256] + b[tid + 256];
}

extern "C" void kernel_launch(void* const* d_in, const int* in_sizes, int n_in,
                              void* d_out, int out_size, void* d_ws, size_t ws_size,
                              hipStream_t stream)
{
    const float* x1   = (const float*)d_in[0];
    const float* x2   = (const float*)d_in[1];
    const float* win1 = (const float*)d_in[2];
    const float* bin1 = (const float*)d_in[3];
    const float* wout1= (const float*)d_in[4];
    const float* bout1= (const float*)d_in[5];
    const float* win2 = (const float*)d_in[6];
    const float* bin2 = (const float*)d_in[7];
    const float* wout2= (const float*)d_in[8];
    const float* bout2= (const float*)d_in[9];
    const float* g1   = (const float*)d_in[10];
    const float* b1   = (const float*)d_in[11];
    const float* g2   = (const float*)d_in[12];
    const float* b2   = (const float*)d_in[13];
    const float* fw1  = (const float*)d_in[14];
    const float* fb1  = (const float*)d_in[15];
    const float* fw2  = (const float*)d_in[16];
    const float* fb2  = (const float*)d_in[17];
    const float* g3   = (const float*)d_in[18];
    const float* b3   = (const float*)d_in[19];

    // Workspace layout (floats): qkv [M x 1536] at 0; ctx [M x 512] after.
    // proj and ffnmid alias the (then-dead) qkv region; ffnout aliases ctx... no:
    // ffnout must coexist with ffnmid reads -> ffnout goes in ctx region (dead then).
    float* ws   = (float*)d_ws;
    float* qkv  = ws;                              // M x 1536 = 12.58M floats
    float* ctx  = qkv + (size_t)MM * 1536;         // M x 512  =  4.19M floats
    float* proj   = qkv;                           // alias: qkv dead after attn
    float* ffnmid = qkv;                           // alias: M x 1024
    float* ffnout = ctx;                           // alias: ctx dead in FFN phase

    float* out     = (float*)d_out;
    float* out_x1  = out;                                    // M x 512 (holds x1ln mid-flight)
    float* out_x2  = out + (size_t)MM * 512;                 // M x 512 (holds x2ln mid-flight)
    float* out_w12 = out_x2 + (size_t)MM * 512;              // B*H*L*L
    float* out_w21 = out_w12 + (size_t)BB * NH * LL * LL;    // B*H*L*L
    float* x1ln = out_x1;
    float* x2ln = out_x2;

    const dim3 blk(256);
    const dim3 g512(8, 128);    // N=512 tiles
    const dim3 g1024(16, 128);  // N=1024 tiles

    // --- attention 1: q from x1, k/v from x2 ---
    gemm_bias<false><<<g512,  blk, 0, stream>>>(x1, win1,            bin1,       qkv,       1536, 512);
    gemm_bias<false><<<g1024, blk, 0, stream>>>(x2, win1 + 512*512,  bin1 + 512, qkv + 512, 1536, 512);
    attn_kernel<<<BB * NH * LL, blk, 0, stream>>>(qkv, out_w12, ctx);
    gemm_bias<false><<<g512,  blk, 0, stream>>>(ctx, wout1, bout1, proj, 512, 512);
    add_ln<<<MM, blk, 0, stream>>>(x1, proj, g1, b1, x1ln);

    // --- attention 2: q from ORIGINAL x2, k/v from updated x1ln ---
    gemm_bias<false><<<g512,  blk, 0, stream>>>(x2,   win2,           bin2,       qkv,       1536, 512);
    gemm_bias<false><<<g1024, blk, 0, stream>>>(x1ln, win2 + 512*512, bin2 + 512, qkv + 512, 1536, 512);
    attn_kernel<<<BB * NH * LL, blk, 0, stream>>>(qkv, out_w21, ctx);
    gemm_bias<false><<<g512,  blk, 0, stream>>>(ctx, wout2, bout2, proj, 512, 512);
    add_ln<<<MM, blk, 0, stream>>>(x2, proj, g2, b2, x2ln);

    // --- FFN 1 on x1ln (in-place final LN into out_x1) ---
    gemm_bias<true><<<g1024, blk, 0, stream>>>(x1ln, fw1, fb1, ffnmid, 1024, 512);
    gemm_bias<false><<<g512, blk, 0, stream>>>(ffnmid, fw2, fb2, ffnout, 512, 1024);
    add_ln<<<MM, blk, 0, stream>>>(x1ln, ffnout, g3, b3, out_x1);

    // --- FFN 2 on x2ln (in-place final LN into out_x2) ---
    gemm_bias<true><<<g1024, blk, 0, stream>>>(x2ln, fw1, fb1, ffnmid, 1024, 512);
    gemm_bias<false><<<g512, blk, 0, stream>>>(ffnmid, fw2, fb2, ffnout, 512, 1024);
    add_ln<<<MM, blk, 0, stream>>>(x2ln, ffnout, g3, b3, out_x2);
}